// Round 6
// baseline (61.103 us; speedup 1.0000x reference)
//
#include <hip/hip_runtime.h>
#include <math.h>
#include <stdint.h>

// Problem constants (b=1, h=8, t=2048, d=64, n=32)
#define BH 8
#define NB 32
#define SS 64
#define DD 64
#define TT 2048

typedef float f32x16 __attribute__((ext_vector_type(16)));
typedef short bf16x8 __attribute__((ext_vector_type(8)));
typedef unsigned short u16;

__device__ __forceinline__ unsigned pkbf(float a, float b) {
  unsigned r;
  asm("v_cvt_pk_bf16_f32 %0, %1, %2" : "=v"(r) : "v"(a), "v"(b));
  return r;
}
__device__ __forceinline__ float exp2x(float x) {
  float r;
  asm("v_exp_f32 %0, %1" : "=v"(r) : "v"(x));
  return r;
}
__device__ __forceinline__ bf16x8 pack8v(const f32x16& v, const int b) {
  union { unsigned u[4]; bf16x8 v8; } x;
  x.u[0] = pkbf(v[b + 0], v[b + 1]);
  x.u[1] = pkbf(v[b + 2], v[b + 3]);
  x.u[2] = pkbf(v[b + 4], v[b + 5]);
  x.u[3] = pkbf(v[b + 6], v[b + 7]);
  return x.v8;
}

// ---------------- Kernel 1: prep (blocks 0..255) + sinkhorn (256..263) ----
__global__ __launch_bounds__(256) void prep_sink_kernel(
    const float* __restrict__ q, const float* __restrict__ k, const float* __restrict__ v,
    const float* __restrict__ gu,
    u16* __restrict__ qb, u16* __restrict__ kb, u16* __restrict__ vtb,
    float* __restrict__ Rm)
{
  __shared__ float smemF[3][64][68];   // prep: qt/kt/vt ; sink: qs/ks/rbuf

  const int bid = blockIdx.x;
  const int t = threadIdx.x;

  if (bid < 256) {
    // ---------------- prep: fragment-major bf16 workspace (R5-verified) ----
    float (*qt)[68] = smemF[0];
    float (*kt)[68] = smemF[1];
    float (*vt)[68] = smemF[2];
    const int T = bid;
    const float* qsrc = q + (size_t)T * 4096;
    const float* ksrc = k + (size_t)T * 4096;
    const float* vsrc = v + (size_t)T * 4096;

#pragma unroll
    for (int r4 = 0; r4 < 4; ++r4) {
      int f = r4 * 256 + t;
      int row = f >> 4, c4 = (f & 15) << 2;
      *(float4*)&qt[row][c4] = ((const float4*)qsrc)[f];
      *(float4*)&kt[row][c4] = ((const float4*)ksrc)[f];
      *(float4*)&vt[row][c4] = ((const float4*)vsrc)[f];
    }
    __syncthreads();

    const float qscale = 0.18033688011112042f;  // 0.125 * log2(e)
#pragma unroll
    for (int half = 0; half < 2; ++half) {
      int x = half * 256 + t;
      int c = x >> 6, lane = x & 63;
      int l31 = lane & 31, hi = lane >> 5;
      int m = c >> 2, s = c & 3;
      int row = l31 + 32 * m;
      int cb = 16 * s + 4 * hi;
      float4 a = *(const float4*)&qt[row][cb];
      float4 b = *(const float4*)&qt[row][cb + 8];
      uint4 o;
      o.x = pkbf(a.x * qscale, a.y * qscale);
      o.y = pkbf(a.z * qscale, a.w * qscale);
      o.z = pkbf(b.x * qscale, b.y * qscale);
      o.w = pkbf(b.z * qscale, b.w * qscale);
      *(uint4*)(qb + (size_t)T * 4096 + (size_t)x * 8) = o;

      float4 ka = *(const float4*)&kt[row][cb];
      float4 kb4 = *(const float4*)&kt[row][cb + 8];
      uint4 ko;
      ko.x = pkbf(ka.x, ka.y);
      ko.y = pkbf(ka.z, ka.w);
      ko.z = pkbf(kb4.x, kb4.y);
      ko.w = pkbf(kb4.z, kb4.w);
      *(uint4*)(kb + (size_t)T * 4096 + (size_t)x * 8) = ko;

      int d = l31 + 32 * m;
      int kb0 = 16 * s + 4 * hi;
      uint4 vo;
      vo.x = pkbf(vt[kb0 + 0][d], vt[kb0 + 1][d]);
      vo.y = pkbf(vt[kb0 + 2][d], vt[kb0 + 3][d]);
      vo.z = pkbf(vt[kb0 + 8][d], vt[kb0 + 9][d]);
      vo.w = pkbf(vt[kb0 + 10][d], vt[kb0 + 11][d]);
      *(uint4*)(vtb + (size_t)T * 4096 + (size_t)x * 8) = vo;
    }
  } else {
    // ---------------- sinkhorn (256 threads, shuffle col-LSE) -------------
    const int bh = bid - 256;
    // bucket sums: thread t -> bucket b = t>>3, dims d8..d8+7
    {
      const int b = t >> 3;
      const int d8 = (t & 7) * 8;
      float sq[8], sk[8];
#pragma unroll
      for (int x = 0; x < 8; ++x) { sq[x] = 0.f; sk[x] = 0.f; }
      const float* qpb = q + ((size_t)bh * 2048 + b * 64) * 64 + d8;
      const float* kpb = k + ((size_t)bh * 2048 + b * 64) * 64 + d8;
      for (int row = 0; row < 64; ++row) {
        float4 a = *(const float4*)(qpb + row * 64);
        float4 b4 = *(const float4*)(qpb + row * 64 + 4);
        sq[0] += a.x; sq[1] += a.y; sq[2] += a.z; sq[3] += a.w;
        sq[4] += b4.x; sq[5] += b4.y; sq[6] += b4.z; sq[7] += b4.w;
        float4 c = *(const float4*)(kpb + row * 64);
        float4 d4 = *(const float4*)(kpb + row * 64 + 4);
        sk[0] += c.x; sk[1] += c.y; sk[2] += c.z; sk[3] += c.w;
        sk[4] += d4.x; sk[5] += d4.y; sk[6] += d4.z; sk[7] += d4.w;
      }
#pragma unroll
      for (int x = 0; x < 8; ++x) {
        smemF[0][b][d8 + x] = sq[x];
        smemF[1][b][d8 + x] = sk[x];
      }
    }
    __syncthreads();

    const int G = t >> 5;     // 0..7
    const int j = t & 31;
    float* rb = &smemF[2][0][0];   // rbuf[32][33] flat
    float* colb = rb + 32 * 33;    // 32 floats

    // logits + gumbel; rows i = G + 8x
    float r4[4];
#pragma unroll
    for (int x = 0; x < 4; ++x) {
      int ii = G + 8 * x;
      float acc = 0.f;
      for (int e = 0; e < 64; ++e) acc += smemF[0][ii][e] * smemF[1][j][e];
      acc *= 0.125f;
      float u = gu[bh * 1024 + ii * 32 + j];
      float g = -logf(-logf(u + 1e-6f) + 1e-6f);
      r4[x] = (logf(fmaxf(acc, 0.f) + 1e-6f) + g) * (1.0f / 0.75f);
    }

    for (int it = 0; it < 7; ++it) {
      // row LSE (over j): width-32 shuffles, lanes of group G share row
#pragma unroll
      for (int x = 0; x < 4; ++x) {
        float m = r4[x];
        m = fmaxf(m, __shfl_xor(m, 16, 32));
        m = fmaxf(m, __shfl_xor(m, 8, 32));
        m = fmaxf(m, __shfl_xor(m, 4, 32));
        m = fmaxf(m, __shfl_xor(m, 2, 32));
        m = fmaxf(m, __shfl_xor(m, 1, 32));
        float s = expf(r4[x] - m);
        s += __shfl_xor(s, 16, 32);
        s += __shfl_xor(s, 8, 32);
        s += __shfl_xor(s, 4, 32);
        s += __shfl_xor(s, 2, 32);
        s += __shfl_xor(s, 1, 32);
        r4[x] -= m + logf(s);
      }
      // col LSE: transpose via LDS, shuffle within 32-groups
#pragma unroll
      for (int x = 0; x < 4; ++x) rb[(G + 8 * x) * 33 + j] = r4[x];
      __syncthreads();
#pragma unroll
      for (int x = 0; x < 4; ++x) {
        float y = rb[j * 33 + (G + 8 * x)];   // column (G+8x), row j
        float m2 = y;
        m2 = fmaxf(m2, __shfl_xor(m2, 16, 32));
        m2 = fmaxf(m2, __shfl_xor(m2, 8, 32));
        m2 = fmaxf(m2, __shfl_xor(m2, 4, 32));
        m2 = fmaxf(m2, __shfl_xor(m2, 2, 32));
        m2 = fmaxf(m2, __shfl_xor(m2, 1, 32));
        float s2 = expf(y - m2);
        s2 += __shfl_xor(s2, 16, 32);
        s2 += __shfl_xor(s2, 8, 32);
        s2 += __shfl_xor(s2, 4, 32);
        s2 += __shfl_xor(s2, 2, 32);
        s2 += __shfl_xor(s2, 1, 32);
        if (j == 0) colb[G + 8 * x] = m2 + logf(s2);
      }
      __syncthreads();
#pragma unroll
      for (int x = 0; x < 4; ++x) r4[x] -= colb[j];
      __syncthreads();
    }

#pragma unroll
    for (int x = 0; x < 4; ++x) {
      float R = expf(r4[x]);
      Rm[bh * 1024 + (G + 8 * x) * 32 + j] = (R > 1e-3f) ? R : 0.f;
    }
  }
}

// ---------------- Kernel 2: MFMA attention, LDS-staged K/V ----------------
// block per (bh,i), bh = bid&7. 512 threads = 8 waves.
// wave w: n = w&1 (q-block of 32 rows), g = w>>1 (j = g + 4*round).
// Round r: 8 tiles staged to LDS (wave w stages K tile w | V tile w-4),
// double-buffered; waves read fragments via ds_read_b128.
__global__ __launch_bounds__(512) void attn_kernel(
    const u16* __restrict__ qb, const u16* __restrict__ kb,
    const u16* __restrict__ vtb, const float* __restrict__ Rm,
    float* __restrict__ out)
{
  __shared__ __align__(16) unsigned char smem[131072];  // 2 bufs x 8 tiles x 8KB
  // post-loop aliases (staging region is dead by then)
  float (*redh)[2][32][68] = (float (*)[2][32][68])smem;       // 34816 B
  float (*cbuf)[32] = (float (*)[32])(smem + 34816);           // 1024 B

  const int bh  = blockIdx.x & 7;
  const int i   = blockIdx.x >> 3;
  const int t   = threadIdx.x;
  const int w   = t >> 6;
  const int n   = w & 1;
  const int g   = w >> 1;
  const int lane = t & 63;
  const int l31 = lane & 31;
  const int hi  = lane >> 5;

  const u16* qtile = qb + ((size_t)(bh * NB + i)) * 4096;
  const u16* kbh   = kb + (size_t)bh * NB * 4096;
  const u16* vbh   = vtb + (size_t)bh * NB * 4096;

#define GLDS(srcp, dstp)                                                      \
  __builtin_amdgcn_global_load_lds(                                           \
      (const __attribute__((address_space(1))) void*)(srcp),                  \
      (__attribute__((address_space(3))) void*)(dstp), 16, 0, 0)

  // wave w stages tile w of round r into buffer p (K tiles 0-3, V tiles 4-7)
#define STAGE(p, r)                                                           \
  {                                                                           \
    const u16* srcT = (w < 4) ? (kbh + (size_t)(w + 4 * (r)) * 4096)          \
                              : (vbh + (size_t)(w - 4 + 4 * (r)) * 4096);     \
    unsigned char* dstT = smem + (p) * 65536 + w * 8192;                      \
    _Pragma("unroll") for (int ii = 0; ii < 8; ++ii)                          \
      GLDS(srcT + (size_t)(ii * 64 + lane) * 8, dstT + ii * 1024);            \
  }

  // fragment load from a staged LDS tile (linear, conflict-free b128)
#define LOADL(dst, p, tile)                                                   \
  {                                                                           \
    const u16* baseL = (const u16*)(smem + (p) * 65536 + (tile) * 8192);      \
    _Pragma("unroll") for (int m = 0; m < 2; ++m)                             \
    _Pragma("unroll") for (int s = 0; s < 4; ++s)                             \
      dst[m][s] = *(const bf16x8*)(baseL + ((m * 4 + s) * 64 + lane) * 8);    \
  }

  // direct global fragment load (self phase / tail only)
#define LOADG(dst, base)                                                      \
  {                                                                           \
    _Pragma("unroll") for (int m = 0; m < 2; ++m)                             \
    _Pragma("unroll") for (int s = 0; s < 4; ++s)                             \
      dst[m][s] = *(const bf16x8*)((base) + ((size_t)((m * 4 + s) * 64 + lane)) * 8); \
  }

  STAGE(0, 0);

  // persistent Q B-fragments
  bf16x8 qB[4];
#pragma unroll
  for (int s = 0; s < 4; ++s)
    qB[s] = *(const bf16x8*)(qtile + ((size_t)((n * 4 + s) * 64 + lane)) * 8);

  // ---- self phase: S_self^T, m0, S0, psA (R4/R5-verified) ----
  float m0, S0;
  bf16x8 psA[4];
  {
    const u16* kib = kbh + (size_t)i * 4096;
    bf16x8 kAi[2][4];
    LOADG(kAi, kib);
    f32x16 aS0, aS1;
#pragma unroll
    for (int r = 0; r < 16; ++r) { aS0[r] = 0.f; aS1[r] = 0.f; }
#pragma unroll
    for (int s = 0; s < 4; ++s) {
      aS0 = __builtin_amdgcn_mfma_f32_32x32x16_bf16(kAi[0][s], qB[s], aS0, 0, 0, 0);
      aS1 = __builtin_amdgcn_mfma_f32_32x32x16_bf16(kAi[1][s], qB[s], aS1, 0, 0, 0);
    }
    float mx[16];
#pragma unroll
    for (int r = 0; r < 16; ++r) mx[r] = fmaxf(aS0[r], aS1[r]);
#pragma unroll
    for (int off = 8; off > 0; off >>= 1)
#pragma unroll
      for (int r = 0; r < off; ++r) mx[r] = fmaxf(mx[r], mx[r + off]);
    float mm = fmaxf(mx[0], __shfl_xor(mx[0], 32, 64));
#pragma unroll
    for (int r = 0; r < 16; ++r) { aS0[r] = exp2x(aS0[r] - mm); aS1[r] = exp2x(aS1[r] - mm); }
    float sm[16];
#pragma unroll
    for (int r = 0; r < 16; ++r) sm[r] = aS0[r] + aS1[r];
#pragma unroll
    for (int off = 8; off > 0; off >>= 1)
#pragma unroll
      for (int r = 0; r < off; ++r) sm[r] += sm[r + off];
    S0 = sm[0] + __shfl_xor(sm[0], 32, 64);
    m0 = mm;
    psA[0] = pack8v(aS0, 0);
    psA[1] = pack8v(aS0, 8);
    psA[2] = pack8v(aS1, 0);
    psA[3] = pack8v(aS1, 8);
  }

  f32x16 outAcc[2];
#pragma unroll
  for (int nv = 0; nv < 2; ++nv)
#pragma unroll
    for (int e = 0; e < 16; ++e) outAcc[nv][e] = 0.f;
  float cacc = 0.f;
  const float* Rrow = Rm + bh * NB * NB + i * NB;
  float rij8[8];
#pragma unroll
  for (int jj = 0; jj < 8; ++jj) rij8[jj] = Rrow[g + 4 * jj];

  // ---- j loop: 8 rounds, double-buffered LDS staging ----
#pragma unroll
  for (int rr = 0; rr < 8; ++rr) {
    const int p = rr & 1;
    asm volatile("s_waitcnt vmcnt(0)" ::: "memory");   // round rr staged
    __builtin_amdgcn_s_barrier();                       // all waves' stages done
    __builtin_amdgcn_sched_barrier(0);
    if (rr < 7) STAGE(p ^ 1, rr + 1);                   // prefetch next round

    const float rij = rij8[rr];
    bf16x8 kA[2][4], vB[2][4];
    LOADL(kA, p, g);
    LOADL(vB, p, 4 + g);

    f32x16 a0, a1;
#pragma unroll
    for (int r = 0; r < 16; ++r) { a0[r] = 0.f; a1[r] = 0.f; }
    __builtin_amdgcn_s_setprio(1);
#pragma unroll
    for (int s = 0; s < 4; ++s) {
      a0 = __builtin_amdgcn_mfma_f32_32x32x16_bf16(kA[0][s], qB[s], a0, 0, 0, 0);
      a1 = __builtin_amdgcn_mfma_f32_32x32x16_bf16(kA[1][s], qB[s], a1, 0, 0, 0);
    }
    __builtin_amdgcn_s_setprio(0);

    float mx[16];
#pragma unroll
    for (int r = 0; r < 16; ++r) mx[r] = fmaxf(a0[r], a1[r]);
#pragma unroll
    for (int off = 8; off > 0; off >>= 1)
#pragma unroll
      for (int r = 0; r < off; ++r) mx[r] = fmaxf(mx[r], mx[r + off]);
    float mc = fmaxf(mx[0], __shfl_xor(mx[0], 32, 64));
    float mj = fmaxf(m0, mc);
#pragma unroll
    for (int r = 0; r < 16; ++r) { a0[r] = exp2x(a0[r] - mj); a1[r] = exp2x(a1[r] - mj); }
    float sm[16];
#pragma unroll
    for (int r = 0; r < 16; ++r) sm[r] = a0[r] + a1[r];
#pragma unroll
    for (int off = 8; off > 0; off >>= 1)
#pragma unroll
      for (int r = 0; r < off; ++r) sm[r] += sm[r + off];
    float ssum = sm[0] + __shfl_xor(sm[0], 32, 64);
    float e0 = exp2x(m0 - mj);
    float den = S0 * e0 + ssum;
    float inv = rij / den;
    cacc += e0 * inv;
#pragma unroll
    for (int r = 0; r < 16; ++r) { a0[r] *= inv; a1[r] *= inv; }

    __builtin_amdgcn_s_setprio(1);
#pragma unroll
    for (int s = 0; s < 4; ++s) {
      bf16x8 wf = (s < 2) ? pack8v(a0, 8 * (s & 1)) : pack8v(a1, 8 * (s & 1));
      outAcc[0] = __builtin_amdgcn_mfma_f32_32x32x16_bf16(wf, vB[0][s], outAcc[0], 0, 0, 0);
      outAcc[1] = __builtin_amdgcn_mfma_f32_32x32x16_bf16(wf, vB[1][s], outAcc[1], 0, 0, 0);
    }
    __builtin_amdgcn_s_setprio(0);
  }

  // ---- per-wave self term: out += cacc(row) * psA @ V_i ----
  {
    const u16* vib = vbh + (size_t)i * 4096;
    bf16x8 vBi[2][4];
    LOADG(vBi, vib);
    f32x16 U[2];
#pragma unroll
    for (int nv = 0; nv < 2; ++nv)
#pragma unroll
      for (int e = 0; e < 16; ++e) U[nv][e] = 0.f;
#pragma unroll
    for (int s = 0; s < 4; ++s) {
      U[0] = __builtin_amdgcn_mfma_f32_32x32x16_bf16(psA[s], vBi[0][s], U[0], 0, 0, 0);
      U[1] = __builtin_amdgcn_mfma_f32_32x32x16_bf16(psA[s], vBi[1][s], U[1], 0, 0, 0);
    }
    if (hi == 0) cbuf[w][l31] = cacc;
    __syncthreads();
#pragma unroll
    for (int r = 0; r < 16; ++r) {
      int row = (r & 3) + 8 * (r >> 2) + 4 * hi;
      float cr = cbuf[w][row];
      outAcc[0][r] += U[0][r] * cr;
      outAcc[1][r] += U[1][r] * cr;
    }
  }

  // ---- per-n 4-wave reduction tree ----
#define RED_W(buf)                                                         \
  {                                                                        \
    _Pragma("unroll") for (int ne = 0; ne < 2; ++ne)                       \
    _Pragma("unroll") for (int r = 0; r < 16; ++r) {                       \
      int row = (r & 3) + 8 * (r >> 2) + 4 * hi;                           \
      (buf)[row][l31 + 32 * ne] = outAcc[ne][r];                           \
    }                                                                      \
  }
#define RED_A(buf)                                                         \
  {                                                                        \
    _Pragma("unroll") for (int ne = 0; ne < 2; ++ne)                       \
    _Pragma("unroll") for (int r = 0; r < 16; ++r) {                       \
      int row = (r & 3) + 8 * (r >> 2) + 4 * hi;                           \
      outAcc[ne][r] += (buf)[row][l31 + 32 * ne];                          \
    }                                                                      \
  }

  if (g >= 2) RED_W(redh[n][g - 2]);
  __syncthreads();
  if (g < 2) RED_A(redh[n][g]);
  __syncthreads();
  if (g == 1) RED_W(redh[n][0]);
  __syncthreads();
  if (g == 0) {
    RED_A(redh[n][0]);
    RED_W(redh[n][0]);
  }
  __syncthreads();

  // coalesced store
  {
    int row = t >> 3;
    int nr = row >> 5, lrow = row & 31;
    int col0 = (t & 7) * 8;
    float4 a = *(const float4*)&redh[nr][0][lrow][col0];
    float4 b = *(const float4*)&redh[nr][0][lrow][col0 + 4];
    float* ob = out + ((size_t)bh * TT + i * SS + row) * DD + col0;
    *(float4*)ob = a;
    *(float4*)(ob + 4) = b;
  }
#undef GLDS
#undef STAGE
#undef LOADL
#undef LOADG
#undef RED_W
#undef RED_A
}

extern "C" void kernel_launch(void* const* d_in, const int* in_sizes, int n_in,
                              void* d_out, int out_size, void* d_ws, size_t ws_size,
                              hipStream_t stream) {
  (void)in_sizes; (void)n_in; (void)out_size; (void)ws_size;
  const float* q  = (const float*)d_in[0];
  const float* k  = (const float*)d_in[1];
  const float* v  = (const float*)d_in[2];
  const float* gu = (const float*)d_in[3];
  float* out = (float*)d_out;

  char* wsb = (char*)d_ws;
  u16* qb   = (u16*)(wsb);
  u16* kb   = (u16*)(wsb + (1 << 21));
  u16* vtb  = (u16*)(wsb + (2 << 21));
  float* Rm = (float*)(wsb + (3 << 21));

  prep_sink_kernel<<<264, 256, 0, stream>>>(q, k, v, gu, qb, kb, vtb, Rm);
  attn_kernel<<<BH * NB, 512, 0, stream>>>(qb, kb, vtb, Rm, out);
}

// Round 7
// 41.542 us; speedup vs baseline: 1.4709x; 1.4709x over previous
//
#include <hip/hip_runtime.h>
#include <math.h>
#include <stdint.h>

// Problem constants (b=1, h=8, t=2048, d=64, n=32)
#define BH 8
#define NB 32
#define SS 64
#define DD 64
#define TT 2048

typedef float f32x16 __attribute__((ext_vector_type(16)));
typedef short bf16x8 __attribute__((ext_vector_type(8)));
typedef unsigned short u16;

__device__ __forceinline__ unsigned pkbf(float a, float b) {
  unsigned r;
  asm("v_cvt_pk_bf16_f32 %0, %1, %2" : "=v"(r) : "v"(a), "v"(b));
  return r;
}
__device__ __forceinline__ float exp2x(float x) {
  float r;
  asm("v_exp_f32 %0, %1" : "=v"(r) : "v"(x));
  return r;
}
__device__ __forceinline__ bf16x8 pack8v(const f32x16& v, const int b) {
  union { unsigned u[4]; bf16x8 v8; } x;
  x.u[0] = pkbf(v[b + 0], v[b + 1]);
  x.u[1] = pkbf(v[b + 2], v[b + 3]);
  x.u[2] = pkbf(v[b + 4], v[b + 5]);
  x.u[3] = pkbf(v[b + 6], v[b + 7]);
  return x.v8;
}

// ---------------- Kernel 1: prep (R5-verified verbatim) -------------------
// One block per tile T = bh*32 + bucket. Fragment-major bf16 workspace +
// per-bucket q/k column sums for the sort-net.
__global__ __launch_bounds__(256) void prep_kernel(
    const float* __restrict__ q, const float* __restrict__ k, const float* __restrict__ v,
    u16* __restrict__ qb, u16* __restrict__ kb, u16* __restrict__ vtb,
    float* __restrict__ qsum, float* __restrict__ ksum)
{
  __shared__ float qt[64][68];
  __shared__ float kt[64][68];
  __shared__ float vt[64][68];

  const int T = blockIdx.x;
  const int t = threadIdx.x;
  const float* qsrc = q + (size_t)T * 4096;
  const float* ksrc = k + (size_t)T * 4096;
  const float* vsrc = v + (size_t)T * 4096;

#pragma unroll
  for (int r4 = 0; r4 < 4; ++r4) {
    int f = r4 * 256 + t;
    int row = f >> 4, c4 = (f & 15) << 2;
    *(float4*)&qt[row][c4] = ((const float4*)qsrc)[f];
    *(float4*)&kt[row][c4] = ((const float4*)ksrc)[f];
    *(float4*)&vt[row][c4] = ((const float4*)vsrc)[f];
  }
  __syncthreads();

  const float qscale = 0.18033688011112042f;  // 0.125 * log2(e)

#pragma unroll
  for (int half = 0; half < 2; ++half) {
    int x = half * 256 + t;
    int c = x >> 6, lane = x & 63;
    int l31 = lane & 31, hi = lane >> 5;
    int m = c >> 2, s = c & 3;
    int row = l31 + 32 * m;
    int cb = 16 * s + 4 * hi;
    float4 a = *(const float4*)&qt[row][cb];
    float4 b = *(const float4*)&qt[row][cb + 8];
    uint4 o;
    o.x = pkbf(a.x * qscale, a.y * qscale);
    o.y = pkbf(a.z * qscale, a.w * qscale);
    o.z = pkbf(b.x * qscale, b.y * qscale);
    o.w = pkbf(b.z * qscale, b.w * qscale);
    *(uint4*)(qb + (size_t)T * 4096 + (size_t)x * 8) = o;

    float4 ka = *(const float4*)&kt[row][cb];
    float4 kb4 = *(const float4*)&kt[row][cb + 8];
    uint4 ko;
    ko.x = pkbf(ka.x, ka.y);
    ko.y = pkbf(ka.z, ka.w);
    ko.z = pkbf(kb4.x, kb4.y);
    ko.w = pkbf(kb4.z, kb4.w);
    *(uint4*)(kb + (size_t)T * 4096 + (size_t)x * 8) = ko;

    int d = l31 + 32 * m;
    int kb0 = 16 * s + 4 * hi;
    uint4 vo;
    vo.x = pkbf(vt[kb0 + 0][d], vt[kb0 + 1][d]);
    vo.y = pkbf(vt[kb0 + 2][d], vt[kb0 + 3][d]);
    vo.z = pkbf(vt[kb0 + 8][d], vt[kb0 + 9][d]);
    vo.w = pkbf(vt[kb0 + 10][d], vt[kb0 + 11][d]);
    *(uint4*)(vtb + (size_t)T * 4096 + (size_t)x * 8) = vo;
  }

  // bucket column sums for the sort-net
  if (t < 64) {
    float s = 0.f;
#pragma unroll 8
    for (int r = 0; r < 64; ++r) s += qt[r][t];
    qsum[T * 64 + t] = s;
  } else if (t < 128) {
    int c = t - 64;
    float s = 0.f;
#pragma unroll 8
    for (int r = 0; r < 64; ++r) s += kt[r][c];
    ksum[T * 64 + c] = s;
  }
}

// ---------------- Kernel 2: MFMA attention + inline per-head Sinkhorn -----
// block per (bh,i), bh = bid&7. 512 threads = 8 waves.
// wave w: n = w&1 (q-block of 32 rows), g = w>>1 (j = g + 4*round).
// Each block redundantly computes its head's full 32x32 Sinkhorn (2 elems
// per thread) from the prep'd bucket sums, keeps only row i.
__global__ __launch_bounds__(512) void attn_kernel(
    const u16* __restrict__ qb, const u16* __restrict__ kb,
    const u16* __restrict__ vtb, const float* __restrict__ qsum,
    const float* __restrict__ ksum, const float* __restrict__ gu,
    float* __restrict__ out)
{
  __shared__ __align__(16) unsigned char smem[131072];  // 2 bufs x 8 tiles x 8KB
  // post-loop aliases (staging region dead by then)
  float (*redh)[2][32][68] = (float (*)[2][32][68])smem;       // 34816 B
  float (*cbuf)[32] = (float (*)[32])(smem + 34816);           // 1024 B

  const int bh  = blockIdx.x & 7;
  const int i   = blockIdx.x >> 3;
  const int t   = threadIdx.x;
  const int w   = t >> 6;
  const int n   = w & 1;
  const int g   = w >> 1;
  const int lane = t & 63;
  const int l31 = lane & 31;
  const int hi  = lane >> 5;

  const u16* qtile = qb + ((size_t)(bh * NB + i)) * 4096;
  const u16* kbh   = kb + (size_t)bh * NB * 4096;
  const u16* vbh   = vtb + (size_t)bh * NB * 4096;

#define GLDS(srcp, dstp)                                                      \
  __builtin_amdgcn_global_load_lds(                                           \
      (const __attribute__((address_space(1))) void*)(srcp),                  \
      (__attribute__((address_space(3))) void*)(dstp), 16, 0, 0)

#define STAGE(p, r)                                                           \
  {                                                                           \
    const u16* srcT = (w < 4) ? (kbh + (size_t)(w + 4 * (r)) * 4096)          \
                              : (vbh + (size_t)(w - 4 + 4 * (r)) * 4096);     \
    unsigned char* dstT = smem + (p) * 65536 + w * 8192;                      \
    _Pragma("unroll") for (int ii = 0; ii < 8; ++ii)                          \
      GLDS(srcT + (size_t)(ii * 64 + lane) * 8, dstT + ii * 1024);            \
  }

#define LOADL(dst, p, tile)                                                   \
  {                                                                           \
    const u16* baseL = (const u16*)(smem + (p) * 65536 + (tile) * 8192);      \
    _Pragma("unroll") for (int m = 0; m < 2; ++m)                             \
    _Pragma("unroll") for (int s = 0; s < 4; ++s)                             \
      dst[m][s] = *(const bf16x8*)(baseL + ((m * 4 + s) * 64 + lane) * 8);    \
  }

#define LOADG(dst, base)                                                      \
  {                                                                           \
    _Pragma("unroll") for (int m = 0; m < 2; ++m)                             \
    _Pragma("unroll") for (int s = 0; s < 4; ++s)                             \
      dst[m][s] = *(const bf16x8*)((base) + ((size_t)((m * 4 + s) * 64 + lane)) * 8); \
  }

  STAGE(0, 0);   // round-0 K/V DMA in flight under the sinkhorn + self phase

  // persistent Q B-fragments
  bf16x8 qB[4];
#pragma unroll
  for (int s = 0; s < 4; ++s)
    qB[s] = *(const bf16x8*)(qtile + ((size_t)((n * 4 + s) * 64 + lane)) * 8);

  // ---- inline per-head Sinkhorn (scratch aliased into staging buf1) ----
  float rij8[8];
  {
    float* qs    = (float*)(smem + 65536);       // [32][65]
    float* ks    = qs + 32 * 65;                 // [32][65]
    float* rbufS = ks + 32 * 65;                 // [32][33]
    float* colb  = rbufS + 32 * 33;              // [32]
    float* RmRow = colb + 32;                    // [32]

    {
      int idx = t * 4;  // 0..2047
      float4 qv = *(const float4*)(qsum + bh * 2048 + idx);
      float4 kv = *(const float4*)(ksum + bh * 2048 + idx);
      int b = idx >> 6, e = idx & 63;
      float* qd = qs + b * 65 + e;
      qd[0] = qv.x; qd[1] = qv.y; qd[2] = qv.z; qd[3] = qv.w;
      float* kd = ks + b * 65 + e;
      kd[0] = kv.x; kd[1] = kv.y; kd[2] = kv.z; kd[3] = kv.w;
    }
    __syncthreads();

    const int G = t >> 5;   // 0..15
    const int j = t & 31;
    float rr2[2];
#pragma unroll
    for (int x = 0; x < 2; ++x) {
      int ii = G + 16 * x;
      float acc = 0.f;
      for (int e = 0; e < 64; ++e) acc += qs[ii * 65 + e] * ks[j * 65 + e];
      acc *= 0.125f;
      float u = gu[bh * 1024 + ii * 32 + j];
      float gg = -logf(-logf(u + 1e-6f) + 1e-6f);
      rr2[x] = (logf(fmaxf(acc, 0.f) + 1e-6f) + gg) * (1.0f / 0.75f);
    }

    for (int it = 0; it < 7; ++it) {
      // row LSE over j (32-lane groups, verified shuffle form)
#pragma unroll
      for (int x = 0; x < 2; ++x) {
        float m = rr2[x];
        m = fmaxf(m, __shfl_xor(m, 16, 32));
        m = fmaxf(m, __shfl_xor(m, 8, 32));
        m = fmaxf(m, __shfl_xor(m, 4, 32));
        m = fmaxf(m, __shfl_xor(m, 2, 32));
        m = fmaxf(m, __shfl_xor(m, 1, 32));
        float s = expf(rr2[x] - m);
        s += __shfl_xor(s, 16, 32);
        s += __shfl_xor(s, 8, 32);
        s += __shfl_xor(s, 4, 32);
        s += __shfl_xor(s, 2, 32);
        s += __shfl_xor(s, 1, 32);
        rr2[x] -= m + logf(s);
      }
      // col LSE via LDS transpose
#pragma unroll
      for (int x = 0; x < 2; ++x) rbufS[(G + 16 * x) * 33 + j] = rr2[x];
      __syncthreads();
#pragma unroll
      for (int x = 0; x < 2; ++x) {
        int col = G + 16 * x;
        float y = rbufS[j * 33 + col];
        float m2 = y;
        m2 = fmaxf(m2, __shfl_xor(m2, 16, 32));
        m2 = fmaxf(m2, __shfl_xor(m2, 8, 32));
        m2 = fmaxf(m2, __shfl_xor(m2, 4, 32));
        m2 = fmaxf(m2, __shfl_xor(m2, 2, 32));
        m2 = fmaxf(m2, __shfl_xor(m2, 1, 32));
        float s2 = expf(y - m2);
        s2 += __shfl_xor(s2, 16, 32);
        s2 += __shfl_xor(s2, 8, 32);
        s2 += __shfl_xor(s2, 4, 32);
        s2 += __shfl_xor(s2, 2, 32);
        s2 += __shfl_xor(s2, 1, 32);
        if (j == 0) colb[col] = m2 + logf(s2);
      }
      __syncthreads();
#pragma unroll
      for (int x = 0; x < 2; ++x) rr2[x] -= colb[j];
    }

#pragma unroll
    for (int x = 0; x < 2; ++x) {
      if (G + 16 * x == i) {
        float R = expf(rr2[x]);
        RmRow[j] = (R > 1e-3f) ? R : 0.f;
      }
    }
    __syncthreads();
#pragma unroll
    for (int jj = 0; jj < 8; ++jj) rij8[jj] = RmRow[g + 4 * jj];
    // round-0 barrier below guarantees all RmRow reads precede buf1 reuse
  }

  // ---- self phase: S_self^T, m0, S0, psA (R4/R5-verified) ----
  float m0, S0;
  bf16x8 psA[4];
  {
    const u16* kib = kbh + (size_t)i * 4096;
    bf16x8 kAi[2][4];
    LOADG(kAi, kib);
    f32x16 aS0, aS1;
#pragma unroll
    for (int r = 0; r < 16; ++r) { aS0[r] = 0.f; aS1[r] = 0.f; }
#pragma unroll
    for (int s = 0; s < 4; ++s) {
      aS0 = __builtin_amdgcn_mfma_f32_32x32x16_bf16(kAi[0][s], qB[s], aS0, 0, 0, 0);
      aS1 = __builtin_amdgcn_mfma_f32_32x32x16_bf16(kAi[1][s], qB[s], aS1, 0, 0, 0);
    }
    float mx[16];
#pragma unroll
    for (int r = 0; r < 16; ++r) mx[r] = fmaxf(aS0[r], aS1[r]);
#pragma unroll
    for (int off = 8; off > 0; off >>= 1)
#pragma unroll
      for (int r = 0; r < off; ++r) mx[r] = fmaxf(mx[r], mx[r + off]);
    float mm = fmaxf(mx[0], __shfl_xor(mx[0], 32, 64));
#pragma unroll
    for (int r = 0; r < 16; ++r) { aS0[r] = exp2x(aS0[r] - mm); aS1[r] = exp2x(aS1[r] - mm); }
    float sm[16];
#pragma unroll
    for (int r = 0; r < 16; ++r) sm[r] = aS0[r] + aS1[r];
#pragma unroll
    for (int off = 8; off > 0; off >>= 1)
#pragma unroll
      for (int r = 0; r < off; ++r) sm[r] += sm[r + off];
    S0 = sm[0] + __shfl_xor(sm[0], 32, 64);
    m0 = mm;
    psA[0] = pack8v(aS0, 0);
    psA[1] = pack8v(aS0, 8);
    psA[2] = pack8v(aS1, 0);
    psA[3] = pack8v(aS1, 8);
  }

  f32x16 outAcc[2];
#pragma unroll
  for (int nv = 0; nv < 2; ++nv)
#pragma unroll
    for (int e = 0; e < 16; ++e) outAcc[nv][e] = 0.f;
  float cacc = 0.f;

  // ---- j loop: 8 rounds, double-buffered LDS staging ----
#pragma unroll
  for (int rr = 0; rr < 8; ++rr) {
    const int p = rr & 1;
    asm volatile("s_waitcnt vmcnt(0)" ::: "memory");   // round rr staged
    __builtin_amdgcn_s_barrier();                       // all waves' stages done
    __builtin_amdgcn_sched_barrier(0);
    if (rr < 7) STAGE(p ^ 1, rr + 1);                   // prefetch next round

    const float rij = rij8[rr];
    bf16x8 kA[2][4], vB[2][4];
    LOADL(kA, p, g);
    LOADL(vB, p, 4 + g);

    f32x16 a0, a1;
#pragma unroll
    for (int r = 0; r < 16; ++r) { a0[r] = 0.f; a1[r] = 0.f; }
    __builtin_amdgcn_s_setprio(1);
#pragma unroll
    for (int s = 0; s < 4; ++s) {
      a0 = __builtin_amdgcn_mfma_f32_32x32x16_bf16(kA[0][s], qB[s], a0, 0, 0, 0);
      a1 = __builtin_amdgcn_mfma_f32_32x32x16_bf16(kA[1][s], qB[s], a1, 0, 0, 0);
    }
    __builtin_amdgcn_s_setprio(0);

    float mx[16];
#pragma unroll
    for (int r = 0; r < 16; ++r) mx[r] = fmaxf(a0[r], a1[r]);
#pragma unroll
    for (int off = 8; off > 0; off >>= 1)
#pragma unroll
      for (int r = 0; r < off; ++r) mx[r] = fmaxf(mx[r], mx[r + off]);
    float mc = fmaxf(mx[0], __shfl_xor(mx[0], 32, 64));
    float mj = fmaxf(m0, mc);
#pragma unroll
    for (int r = 0; r < 16; ++r) { a0[r] = exp2x(a0[r] - mj); a1[r] = exp2x(a1[r] - mj); }
    float sm[16];
#pragma unroll
    for (int r = 0; r < 16; ++r) sm[r] = a0[r] + a1[r];
#pragma unroll
    for (int off = 8; off > 0; off >>= 1)
#pragma unroll
      for (int r = 0; r < off; ++r) sm[r] += sm[r + off];
    float ssum = sm[0] + __shfl_xor(sm[0], 32, 64);
    float e0 = exp2x(m0 - mj);
    float den = S0 * e0 + ssum;
    float inv = rij / den;
    cacc += e0 * inv;
#pragma unroll
    for (int r = 0; r < 16; ++r) { a0[r] *= inv; a1[r] *= inv; }

    __builtin_amdgcn_s_setprio(1);
#pragma unroll
    for (int s = 0; s < 4; ++s) {
      bf16x8 wf = (s < 2) ? pack8v(a0, 8 * (s & 1)) : pack8v(a1, 8 * (s & 1));
      outAcc[0] = __builtin_amdgcn_mfma_f32_32x32x16_bf16(wf, vB[0][s], outAcc[0], 0, 0, 0);
      outAcc[1] = __builtin_amdgcn_mfma_f32_32x32x16_bf16(wf, vB[1][s], outAcc[1], 0, 0, 0);
    }
    __builtin_amdgcn_s_setprio(0);
  }

  // ---- per-wave self term: out += cacc(row) * psA @ V_i ----
  {
    const u16* vib = vbh + (size_t)i * 4096;
    bf16x8 vBi[2][4];
    LOADG(vBi, vib);
    f32x16 U[2];
#pragma unroll
    for (int nv = 0; nv < 2; ++nv)
#pragma unroll
      for (int e = 0; e < 16; ++e) U[nv][e] = 0.f;
#pragma unroll
    for (int s = 0; s < 4; ++s) {
      U[0] = __builtin_amdgcn_mfma_f32_32x32x16_bf16(psA[s], vBi[0][s], U[0], 0, 0, 0);
      U[1] = __builtin_amdgcn_mfma_f32_32x32x16_bf16(psA[s], vBi[1][s], U[1], 0, 0, 0);
    }
    if (hi == 0) cbuf[w][l31] = cacc;
    __syncthreads();
#pragma unroll
    for (int r = 0; r < 16; ++r) {
      int row = (r & 3) + 8 * (r >> 2) + 4 * hi;
      float cr = cbuf[w][row];
      outAcc[0][r] += U[0][r] * cr;
      outAcc[1][r] += U[1][r] * cr;
    }
  }

  // ---- per-n 4-wave reduction tree ----
#define RED_W(buf)                                                         \
  {                                                                        \
    _Pragma("unroll") for (int ne = 0; ne < 2; ++ne)                       \
    _Pragma("unroll") for (int r = 0; r < 16; ++r) {                       \
      int row = (r & 3) + 8 * (r >> 2) + 4 * hi;                           \
      (buf)[row][l31 + 32 * ne] = outAcc[ne][r];                           \
    }                                                                      \
  }
#define RED_A(buf)                                                         \
  {                                                                        \
    _Pragma("unroll") for (int ne = 0; ne < 2; ++ne)                       \
    _Pragma("unroll") for (int r = 0; r < 16; ++r) {                       \
      int row = (r & 3) + 8 * (r >> 2) + 4 * hi;                           \
      outAcc[ne][r] += (buf)[row][l31 + 32 * ne];                          \
    }                                                                      \
  }

  if (g >= 2) RED_W(redh[n][g - 2]);
  __syncthreads();
  if (g < 2) RED_A(redh[n][g]);
  __syncthreads();
  if (g == 1) RED_W(redh[n][0]);
  __syncthreads();
  if (g == 0) {
    RED_A(redh[n][0]);
    RED_W(redh[n][0]);
  }
  __syncthreads();

  // coalesced store
  {
    int row = t >> 3;
    int nr = row >> 5, lrow = row & 31;
    int col0 = (t & 7) * 8;
    float4 a = *(const float4*)&redh[nr][0][lrow][col0];
    float4 b = *(const float4*)&redh[nr][0][lrow][col0 + 4];
    float* ob = out + ((size_t)bh * TT + i * SS + row) * DD + col0;
    *(float4*)ob = a;
    *(float4*)(ob + 4) = b;
  }
#undef GLDS
#undef STAGE
#undef LOADL
#undef LOADG
#undef RED_W
#undef RED_A
}

extern "C" void kernel_launch(void* const* d_in, const int* in_sizes, int n_in,
                              void* d_out, int out_size, void* d_ws, size_t ws_size,
                              hipStream_t stream) {
  (void)in_sizes; (void)n_in; (void)out_size; (void)ws_size;
  const float* q  = (const float*)d_in[0];
  const float* k  = (const float*)d_in[1];
  const float* v  = (const float*)d_in[2];
  const float* gu = (const float*)d_in[3];
  float* out = (float*)d_out;

  char* wsb = (char*)d_ws;
  u16* qb   = (u16*)(wsb);
  u16* kb   = (u16*)(wsb + (1 << 21));
  u16* vtb  = (u16*)(wsb + (2 << 21));
  float* qsum = (float*)(wsb + (3 << 21));
  float* ksum = (float*)(wsb + (3 << 21) + (1 << 16));

  prep_kernel<<<256, 256, 0, stream>>>(q, k, v, qb, kb, vtb, qsum, ksum);
  attn_kernel<<<BH * NB, 512, 0, stream>>>(qb, kb, vtb, qsum, ksum, gu, out);
}

// Round 8
// 36.412 us; speedup vs baseline: 1.6781x; 1.1409x over previous
//
#include <hip/hip_runtime.h>
#include <math.h>
#include <stdint.h>

// Problem constants (b=1, h=8, t=2048, d=64, n=32)
#define BH 8
#define NB 32
#define SS 64
#define DD 64
#define TT 2048

typedef float f32x16 __attribute__((ext_vector_type(16)));
typedef short bf16x8 __attribute__((ext_vector_type(8)));
typedef unsigned short u16;

__device__ __forceinline__ unsigned pkbf(float a, float b) {
  unsigned r;
  asm("v_cvt_pk_bf16_f32 %0, %1, %2" : "=v"(r) : "v"(a), "v"(b));
  return r;
}
__device__ __forceinline__ float exp2x(float x) {
  float r;
  asm("v_exp_f32 %0, %1" : "=v"(r) : "v"(x));
  return r;
}
__device__ __forceinline__ float log2x(float x) {
  float r;
  asm("v_log_f32 %0, %1" : "=v"(r) : "v"(x));
  return r;
}
__device__ __forceinline__ bf16x8 pack8v(const f32x16& v, const int b) {
  union { unsigned u[4]; bf16x8 v8; } x;
  x.u[0] = pkbf(v[b + 0], v[b + 1]);
  x.u[1] = pkbf(v[b + 2], v[b + 3]);
  x.u[2] = pkbf(v[b + 4], v[b + 5]);
  x.u[3] = pkbf(v[b + 6], v[b + 7]);
  return x.v8;
}

// ---------------- Kernel 1: prep (R5-verified verbatim) -------------------
__global__ __launch_bounds__(256) void prep_kernel(
    const float* __restrict__ q, const float* __restrict__ k, const float* __restrict__ v,
    u16* __restrict__ qb, u16* __restrict__ kb, u16* __restrict__ vtb,
    float* __restrict__ qsum, float* __restrict__ ksum)
{
  __shared__ float qt[64][68];
  __shared__ float kt[64][68];
  __shared__ float vt[64][68];

  const int T = blockIdx.x;
  const int t = threadIdx.x;
  const float* qsrc = q + (size_t)T * 4096;
  const float* ksrc = k + (size_t)T * 4096;
  const float* vsrc = v + (size_t)T * 4096;

#pragma unroll
  for (int r4 = 0; r4 < 4; ++r4) {
    int f = r4 * 256 + t;
    int row = f >> 4, c4 = (f & 15) << 2;
    *(float4*)&qt[row][c4] = ((const float4*)qsrc)[f];
    *(float4*)&kt[row][c4] = ((const float4*)ksrc)[f];
    *(float4*)&vt[row][c4] = ((const float4*)vsrc)[f];
  }
  __syncthreads();

  const float qscale = 0.18033688011112042f;  // 0.125 * log2(e)

#pragma unroll
  for (int half = 0; half < 2; ++half) {
    int x = half * 256 + t;
    int c = x >> 6, lane = x & 63;
    int l31 = lane & 31, hi = lane >> 5;
    int m = c >> 2, s = c & 3;
    int row = l31 + 32 * m;
    int cb = 16 * s + 4 * hi;
    float4 a = *(const float4*)&qt[row][cb];
    float4 b = *(const float4*)&qt[row][cb + 8];
    uint4 o;
    o.x = pkbf(a.x * qscale, a.y * qscale);
    o.y = pkbf(a.z * qscale, a.w * qscale);
    o.z = pkbf(b.x * qscale, b.y * qscale);
    o.w = pkbf(b.z * qscale, b.w * qscale);
    *(uint4*)(qb + (size_t)T * 4096 + (size_t)x * 8) = o;

    float4 ka = *(const float4*)&kt[row][cb];
    float4 kb4 = *(const float4*)&kt[row][cb + 8];
    uint4 ko;
    ko.x = pkbf(ka.x, ka.y);
    ko.y = pkbf(ka.z, ka.w);
    ko.z = pkbf(kb4.x, kb4.y);
    ko.w = pkbf(kb4.z, kb4.w);
    *(uint4*)(kb + (size_t)T * 4096 + (size_t)x * 8) = ko;

    int d = l31 + 32 * m;
    int kb0 = 16 * s + 4 * hi;
    uint4 vo;
    vo.x = pkbf(vt[kb0 + 0][d], vt[kb0 + 1][d]);
    vo.y = pkbf(vt[kb0 + 2][d], vt[kb0 + 3][d]);
    vo.z = pkbf(vt[kb0 + 8][d], vt[kb0 + 9][d]);
    vo.w = pkbf(vt[kb0 + 10][d], vt[kb0 + 11][d]);
    *(uint4*)(vtb + (size_t)T * 4096 + (size_t)x * 8) = vo;
  }

  // bucket column sums for the sort-net
  if (t < 64) {
    float s = 0.f;
#pragma unroll 8
    for (int r = 0; r < 64; ++r) s += qt[r][t];
    qsum[T * 64 + t] = s;
  } else if (t < 128) {
    int c = t - 64;
    float s = 0.f;
#pragma unroll 8
    for (int r = 0; r < 64; ++r) s += kt[r][c];
    ksum[T * 64 + c] = s;
  }
}

// ---------------- Kernel 2: MFMA attention + inline per-head Sinkhorn -----
// R7 structure; only the Sinkhorn LSE internals changed: maxless LSE using
// raw v_exp/v_log (log2 domain), 1e-30 clamp for inf-safety.
__global__ __launch_bounds__(512) void attn_kernel(
    const u16* __restrict__ qb, const u16* __restrict__ kb,
    const u16* __restrict__ vtb, const float* __restrict__ qsum,
    const float* __restrict__ ksum, const float* __restrict__ gu,
    float* __restrict__ out)
{
  __shared__ __align__(16) unsigned char smem[131072];  // 2 bufs x 8 tiles x 8KB
  float (*redh)[2][32][68] = (float (*)[2][32][68])smem;       // 34816 B
  float (*cbuf)[32] = (float (*)[32])(smem + 34816);           // 1024 B

  const int bh  = blockIdx.x & 7;
  const int i   = blockIdx.x >> 3;
  const int t   = threadIdx.x;
  const int w   = t >> 6;
  const int n   = w & 1;
  const int g   = w >> 1;
  const int lane = t & 63;
  const int l31 = lane & 31;
  const int hi  = lane >> 5;

  const u16* qtile = qb + ((size_t)(bh * NB + i)) * 4096;
  const u16* kbh   = kb + (size_t)bh * NB * 4096;
  const u16* vbh   = vtb + (size_t)bh * NB * 4096;

#define GLDS(srcp, dstp)                                                      \
  __builtin_amdgcn_global_load_lds(                                           \
      (const __attribute__((address_space(1))) void*)(srcp),                  \
      (__attribute__((address_space(3))) void*)(dstp), 16, 0, 0)

#define STAGE(p, r)                                                           \
  {                                                                           \
    const u16* srcT = (w < 4) ? (kbh + (size_t)(w + 4 * (r)) * 4096)          \
                              : (vbh + (size_t)(w - 4 + 4 * (r)) * 4096);     \
    unsigned char* dstT = smem + (p) * 65536 + w * 8192;                      \
    _Pragma("unroll") for (int ii = 0; ii < 8; ++ii)                          \
      GLDS(srcT + (size_t)(ii * 64 + lane) * 8, dstT + ii * 1024);            \
  }

#define LOADL(dst, p, tile)                                                   \
  {                                                                           \
    const u16* baseL = (const u16*)(smem + (p) * 65536 + (tile) * 8192);      \
    _Pragma("unroll") for (int m = 0; m < 2; ++m)                             \
    _Pragma("unroll") for (int s = 0; s < 4; ++s)                             \
      dst[m][s] = *(const bf16x8*)(baseL + ((m * 4 + s) * 64 + lane) * 8);    \
  }

#define LOADG(dst, base)                                                      \
  {                                                                           \
    _Pragma("unroll") for (int m = 0; m < 2; ++m)                             \
    _Pragma("unroll") for (int s = 0; s < 4; ++s)                             \
      dst[m][s] = *(const bf16x8*)((base) + ((size_t)((m * 4 + s) * 64 + lane)) * 8); \
  }

  STAGE(0, 0);   // round-0 K/V DMA in flight under the sinkhorn + self phase

  // persistent Q B-fragments
  bf16x8 qB[4];
#pragma unroll
  for (int s = 0; s < 4; ++s)
    qB[s] = *(const bf16x8*)(qtile + ((size_t)((n * 4 + s) * 64 + lane)) * 8);

  // ---- inline per-head Sinkhorn (scratch aliased into staging buf1) ----
  float rij8[8];
  {
    const float L2E = 1.4426950408889634f;
    const float LN2 = 0.6931471805599453f;
    float* qs    = (float*)(smem + 65536);       // [32][65]
    float* ks    = qs + 32 * 65;                 // [32][65]
    float* rbufS = ks + 32 * 65;                 // [32][33]
    float* colb  = rbufS + 32 * 33;              // [32]
    float* RmRow = colb + 32;                    // [32]

    {
      int idx = t * 4;  // 0..2047
      float4 qv = *(const float4*)(qsum + bh * 2048 + idx);
      float4 kv = *(const float4*)(ksum + bh * 2048 + idx);
      int b = idx >> 6, e = idx & 63;
      float* qd = qs + b * 65 + e;
      qd[0] = qv.x; qd[1] = qv.y; qd[2] = qv.z; qd[3] = qv.w;
      float* kd = ks + b * 65 + e;
      kd[0] = kv.x; kd[1] = kv.y; kd[2] = kv.z; kd[3] = kv.w;
    }
    __syncthreads();

    const int G = t >> 5;   // 0..15
    const int j = t & 31;
    float rr2[2];
#pragma unroll
    for (int x = 0; x < 2; ++x) {
      int ii = G + 16 * x;
      float acc = 0.f;
      for (int e = 0; e < 64; ++e) acc += qs[ii * 65 + e] * ks[j * 65 + e];
      acc *= 0.125f;
      float u = gu[bh * 1024 + ii * 32 + j];
      float gg = -logf(-logf(u + 1e-6f) + 1e-6f);
      rr2[x] = (logf(fmaxf(acc, 0.f) + 1e-6f) + gg) * (1.0f / 0.75f);
    }

    for (int it = 0; it < 7; ++it) {
      // row LSE over j: maxless, raw exp2/log2 (values provably in fp32 range)
#pragma unroll
      for (int x = 0; x < 2; ++x) {
        float s = exp2x(rr2[x] * L2E);
        s += __shfl_xor(s, 16, 32);
        s += __shfl_xor(s, 8, 32);
        s += __shfl_xor(s, 4, 32);
        s += __shfl_xor(s, 2, 32);
        s += __shfl_xor(s, 1, 32);
        rr2[x] -= log2x(fmaxf(s, 1e-30f)) * LN2;
      }
      // col LSE via LDS transpose, maxless
#pragma unroll
      for (int x = 0; x < 2; ++x) rbufS[(G + 16 * x) * 33 + j] = rr2[x];
      __syncthreads();
#pragma unroll
      for (int x = 0; x < 2; ++x) {
        int col = G + 16 * x;
        float s2 = exp2x(rbufS[j * 33 + col] * L2E);
        s2 += __shfl_xor(s2, 16, 32);
        s2 += __shfl_xor(s2, 8, 32);
        s2 += __shfl_xor(s2, 4, 32);
        s2 += __shfl_xor(s2, 2, 32);
        s2 += __shfl_xor(s2, 1, 32);
        if (j == 0) colb[col] = log2x(fmaxf(s2, 1e-30f)) * LN2;
      }
      __syncthreads();
#pragma unroll
      for (int x = 0; x < 2; ++x) rr2[x] -= colb[j];
    }

#pragma unroll
    for (int x = 0; x < 2; ++x) {
      if (G + 16 * x == i) {
        float R = exp2x(rr2[x] * L2E);
        RmRow[j] = (R > 1e-3f) ? R : 0.f;
      }
    }
    __syncthreads();
#pragma unroll
    for (int jj = 0; jj < 8; ++jj) rij8[jj] = RmRow[g + 4 * jj];
  }

  // ---- self phase: S_self^T, m0, S0, psA (R4/R5-verified) ----
  float m0, S0;
  bf16x8 psA[4];
  {
    const u16* kib = kbh + (size_t)i * 4096;
    bf16x8 kAi[2][4];
    LOADG(kAi, kib);
    f32x16 aS0, aS1;
#pragma unroll
    for (int r = 0; r < 16; ++r) { aS0[r] = 0.f; aS1[r] = 0.f; }
#pragma unroll
    for (int s = 0; s < 4; ++s) {
      aS0 = __builtin_amdgcn_mfma_f32_32x32x16_bf16(kAi[0][s], qB[s], aS0, 0, 0, 0);
      aS1 = __builtin_amdgcn_mfma_f32_32x32x16_bf16(kAi[1][s], qB[s], aS1, 0, 0, 0);
    }
    float mx[16];
#pragma unroll
    for (int r = 0; r < 16; ++r) mx[r] = fmaxf(aS0[r], aS1[r]);
#pragma unroll
    for (int off = 8; off > 0; off >>= 1)
#pragma unroll
      for (int r = 0; r < off; ++r) mx[r] = fmaxf(mx[r], mx[r + off]);
    float mm = fmaxf(mx[0], __shfl_xor(mx[0], 32, 64));
#pragma unroll
    for (int r = 0; r < 16; ++r) { aS0[r] = exp2x(aS0[r] - mm); aS1[r] = exp2x(aS1[r] - mm); }
    float sm[16];
#pragma unroll
    for (int r = 0; r < 16; ++r) sm[r] = aS0[r] + aS1[r];
#pragma unroll
    for (int off = 8; off > 0; off >>= 1)
#pragma unroll
      for (int r = 0; r < off; ++r) sm[r] += sm[r + off];
    S0 = sm[0] + __shfl_xor(sm[0], 32, 64);
    m0 = mm;
    psA[0] = pack8v(aS0, 0);
    psA[1] = pack8v(aS0, 8);
    psA[2] = pack8v(aS1, 0);
    psA[3] = pack8v(aS1, 8);
  }

  f32x16 outAcc[2];
#pragma unroll
  for (int nv = 0; nv < 2; ++nv)
#pragma unroll
    for (int e = 0; e < 16; ++e) outAcc[nv][e] = 0.f;
  float cacc = 0.f;

  // ---- j loop: 8 rounds, double-buffered LDS staging ----
#pragma unroll
  for (int rr = 0; rr < 8; ++rr) {
    const int p = rr & 1;
    asm volatile("s_waitcnt vmcnt(0)" ::: "memory");   // round rr staged
    __builtin_amdgcn_s_barrier();                       // all waves' stages done
    __builtin_amdgcn_sched_barrier(0);
    if (rr < 7) STAGE(p ^ 1, rr + 1);                   // prefetch next round

    const float rij = rij8[rr];
    bf16x8 kA[2][4], vB[2][4];
    LOADL(kA, p, g);
    LOADL(vB, p, 4 + g);

    f32x16 a0, a1;
#pragma unroll
    for (int r = 0; r < 16; ++r) { a0[r] = 0.f; a1[r] = 0.f; }
    __builtin_amdgcn_s_setprio(1);
#pragma unroll
    for (int s = 0; s < 4; ++s) {
      a0 = __builtin_amdgcn_mfma_f32_32x32x16_bf16(kA[0][s], qB[s], a0, 0, 0, 0);
      a1 = __builtin_amdgcn_mfma_f32_32x32x16_bf16(kA[1][s], qB[s], a1, 0, 0, 0);
    }
    __builtin_amdgcn_s_setprio(0);

    float mx[16];
#pragma unroll
    for (int r = 0; r < 16; ++r) mx[r] = fmaxf(a0[r], a1[r]);
#pragma unroll
    for (int off = 8; off > 0; off >>= 1)
#pragma unroll
      for (int r = 0; r < off; ++r) mx[r] = fmaxf(mx[r], mx[r + off]);
    float mc = fmaxf(mx[0], __shfl_xor(mx[0], 32, 64));
    float mj = fmaxf(m0, mc);
#pragma unroll
    for (int r = 0; r < 16; ++r) { a0[r] = exp2x(a0[r] - mj); a1[r] = exp2x(a1[r] - mj); }
    float sm[16];
#pragma unroll
    for (int r = 0; r < 16; ++r) sm[r] = a0[r] + a1[r];
#pragma unroll
    for (int off = 8; off > 0; off >>= 1)
#pragma unroll
      for (int r = 0; r < off; ++r) sm[r] += sm[r + off];
    float ssum = sm[0] + __shfl_xor(sm[0], 32, 64);
    float e0 = exp2x(m0 - mj);
    float den = S0 * e0 + ssum;
    float inv = rij / den;
    cacc += e0 * inv;
#pragma unroll
    for (int r = 0; r < 16; ++r) { a0[r] *= inv; a1[r] *= inv; }

    __builtin_amdgcn_s_setprio(1);
#pragma unroll
    for (int s = 0; s < 4; ++s) {
      bf16x8 wf = (s < 2) ? pack8v(a0, 8 * (s & 1)) : pack8v(a1, 8 * (s & 1));
      outAcc[0] = __builtin_amdgcn_mfma_f32_32x32x16_bf16(wf, vB[0][s], outAcc[0], 0, 0, 0);
      outAcc[1] = __builtin_amdgcn_mfma_f32_32x32x16_bf16(wf, vB[1][s], outAcc[1], 0, 0, 0);
    }
    __builtin_amdgcn_s_setprio(0);
  }

  // ---- per-wave self term: out += cacc(row) * psA @ V_i ----
  {
    const u16* vib = vbh + (size_t)i * 4096;
    bf16x8 vBi[2][4];
    LOADG(vBi, vib);
    f32x16 U[2];
#pragma unroll
    for (int nv = 0; nv < 2; ++nv)
#pragma unroll
      for (int e = 0; e < 16; ++e) U[nv][e] = 0.f;
#pragma unroll
    for (int s = 0; s < 4; ++s) {
      U[0] = __builtin_amdgcn_mfma_f32_32x32x16_bf16(psA[s], vBi[0][s], U[0], 0, 0, 0);
      U[1] = __builtin_amdgcn_mfma_f32_32x32x16_bf16(psA[s], vBi[1][s], U[1], 0, 0, 0);
    }
    if (hi == 0) cbuf[w][l31] = cacc;
    __syncthreads();
#pragma unroll
    for (int r = 0; r < 16; ++r) {
      int row = (r & 3) + 8 * (r >> 2) + 4 * hi;
      float cr = cbuf[w][row];
      outAcc[0][r] += U[0][r] * cr;
      outAcc[1][r] += U[1][r] * cr;
    }
  }

  // ---- per-n 4-wave reduction tree ----
#define RED_W(buf)                                                         \
  {                                                                        \
    _Pragma("unroll") for (int ne = 0; ne < 2; ++ne)                       \
    _Pragma("unroll") for (int r = 0; r < 16; ++r) {                       \
      int row = (r & 3) + 8 * (r >> 2) + 4 * hi;                           \
      (buf)[row][l31 + 32 * ne] = outAcc[ne][r];                           \
    }                                                                      \
  }
#define RED_A(buf)                                                         \
  {                                                                        \
    _Pragma("unroll") for (int ne = 0; ne < 2; ++ne)                       \
    _Pragma("unroll") for (int r = 0; r < 16; ++r) {                       \
      int row = (r & 3) + 8 * (r >> 2) + 4 * hi;                           \
      outAcc[ne][r] += (buf)[row][l31 + 32 * ne];                          \
    }                                                                      \
  }

  if (g >= 2) RED_W(redh[n][g - 2]);
  __syncthreads();
  if (g < 2) RED_A(redh[n][g]);
  __syncthreads();
  if (g == 1) RED_W(redh[n][0]);
  __syncthreads();
  if (g == 0) {
    RED_A(redh[n][0]);
    RED_W(redh[n][0]);
  }
  __syncthreads();

  // coalesced store
  {
    int row = t >> 3;
    int nr = row >> 5, lrow = row & 31;
    int col0 = (t & 7) * 8;
    float4 a = *(const float4*)&redh[nr][0][lrow][col0];
    float4 b = *(const float4*)&redh[nr][0][lrow][col0 + 4];
    float* ob = out + ((size_t)bh * TT + i * SS + row) * DD + col0;
    *(float4*)ob = a;
    *(float4*)(ob + 4) = b;
  }
#undef GLDS
#undef STAGE
#undef LOADL
#undef LOADG
#undef RED_W
#undef RED_A
}

extern "C" void kernel_launch(void* const* d_in, const int* in_sizes, int n_in,
                              void* d_out, int out_size, void* d_ws, size_t ws_size,
                              hipStream_t stream) {
  (void)in_sizes; (void)n_in; (void)out_size; (void)ws_size;
  const float* q  = (const float*)d_in[0];
  const float* k  = (const float*)d_in[1];
  const float* v  = (const float*)d_in[2];
  const float* gu = (const float*)d_in[3];
  float* out = (float*)d_out;

  char* wsb = (char*)d_ws;
  u16* qb   = (u16*)(wsb);
  u16* kb   = (u16*)(wsb + (1 << 21));
  u16* vtb  = (u16*)(wsb + (2 << 21));
  float* qsum = (float*)(wsb + (3 << 21));
  float* ksum = (float*)(wsb + (3 << 21) + (1 << 16));

  prep_kernel<<<256, 256, 0, stream>>>(q, k, v, qb, kb, vtb, qsum, ksum);
  attn_kernel<<<BH * NB, 512, 0, stream>>>(qb, kb, vtb, qsum, ksum, gu, out);
}

// Round 9
// 34.257 us; speedup vs baseline: 1.7836x; 1.0629x over previous
//
#include <hip/hip_runtime.h>
#include <math.h>
#include <stdint.h>

// Problem constants (b=1, h=8, t=2048, d=64, n=32)
#define BH 8
#define NB 32
#define SS 64
#define DD 64
#define TT 2048

typedef float f32x16 __attribute__((ext_vector_type(16)));
typedef short bf16x8 __attribute__((ext_vector_type(8)));
typedef unsigned short u16;

__device__ __forceinline__ unsigned pkbf(float a, float b) {
  unsigned r;
  asm("v_cvt_pk_bf16_f32 %0, %1, %2" : "=v"(r) : "v"(a), "v"(b));
  return r;
}
__device__ __forceinline__ float exp2x(float x) {
  float r;
  asm("v_exp_f32 %0, %1" : "=v"(r) : "v"(x));
  return r;
}
__device__ __forceinline__ float log2x(float x) {
  float r;
  asm("v_log_f32 %0, %1" : "=v"(r) : "v"(x));
  return r;
}
__device__ __forceinline__ bf16x8 pack8v(const f32x16& v, const int b) {
  union { unsigned u[4]; bf16x8 v8; } x;
  x.u[0] = pkbf(v[b + 0], v[b + 1]);
  x.u[1] = pkbf(v[b + 2], v[b + 3]);
  x.u[2] = pkbf(v[b + 4], v[b + 5]);
  x.u[3] = pkbf(v[b + 6], v[b + 7]);
  return x.v8;
}

// ---------------- Kernel 1: prep (R5-verified verbatim) -------------------
__global__ __launch_bounds__(256) void prep_kernel(
    const float* __restrict__ q, const float* __restrict__ k, const float* __restrict__ v,
    u16* __restrict__ qb, u16* __restrict__ kb, u16* __restrict__ vtb,
    float* __restrict__ qsum, float* __restrict__ ksum)
{
  __shared__ float qt[64][68];
  __shared__ float kt[64][68];
  __shared__ float vt[64][68];

  const int T = blockIdx.x;
  const int t = threadIdx.x;
  const float* qsrc = q + (size_t)T * 4096;
  const float* ksrc = k + (size_t)T * 4096;
  const float* vsrc = v + (size_t)T * 4096;

#pragma unroll
  for (int r4 = 0; r4 < 4; ++r4) {
    int f = r4 * 256 + t;
    int row = f >> 4, c4 = (f & 15) << 2;
    *(float4*)&qt[row][c4] = ((const float4*)qsrc)[f];
    *(float4*)&kt[row][c4] = ((const float4*)ksrc)[f];
    *(float4*)&vt[row][c4] = ((const float4*)vsrc)[f];
  }
  __syncthreads();

  const float qscale = 0.18033688011112042f;  // 0.125 * log2(e)

#pragma unroll
  for (int half = 0; half < 2; ++half) {
    int x = half * 256 + t;
    int c = x >> 6, lane = x & 63;
    int l31 = lane & 31, hi = lane >> 5;
    int m = c >> 2, s = c & 3;
    int row = l31 + 32 * m;
    int cb = 16 * s + 4 * hi;
    float4 a = *(const float4*)&qt[row][cb];
    float4 b = *(const float4*)&qt[row][cb + 8];
    uint4 o;
    o.x = pkbf(a.x * qscale, a.y * qscale);
    o.y = pkbf(a.z * qscale, a.w * qscale);
    o.z = pkbf(b.x * qscale, b.y * qscale);
    o.w = pkbf(b.z * qscale, b.w * qscale);
    *(uint4*)(qb + (size_t)T * 4096 + (size_t)x * 8) = o;

    float4 ka = *(const float4*)&kt[row][cb];
    float4 kb4 = *(const float4*)&kt[row][cb + 8];
    uint4 ko;
    ko.x = pkbf(ka.x, ka.y);
    ko.y = pkbf(ka.z, ka.w);
    ko.z = pkbf(kb4.x, kb4.y);
    ko.w = pkbf(kb4.z, kb4.w);
    *(uint4*)(kb + (size_t)T * 4096 + (size_t)x * 8) = ko;

    int d = l31 + 32 * m;
    int kb0 = 16 * s + 4 * hi;
    uint4 vo;
    vo.x = pkbf(vt[kb0 + 0][d], vt[kb0 + 1][d]);
    vo.y = pkbf(vt[kb0 + 2][d], vt[kb0 + 3][d]);
    vo.z = pkbf(vt[kb0 + 8][d], vt[kb0 + 9][d]);
    vo.w = pkbf(vt[kb0 + 10][d], vt[kb0 + 11][d]);
    *(uint4*)(vtb + (size_t)T * 4096 + (size_t)x * 8) = vo;
  }

  // bucket column sums for the sort-net
  if (t < 64) {
    float s = 0.f;
#pragma unroll 8
    for (int r = 0; r < 64; ++r) s += qt[r][t];
    qsum[T * 64 + t] = s;
  } else if (t < 128) {
    int c = t - 64;
    float s = 0.f;
#pragma unroll 8
    for (int r = 0; r < 64; ++r) s += kt[r][c];
    ksum[T * 64 + c] = s;
  }
}

// ---------------- Kernel 2: MFMA attention, direct-L2, 2 blocks/CU --------
// block per (bh,i), bh = bid&7. 512 threads = 8 waves.
// wave w: n = w&1 (q-block), g = w>>1 (j = g + 4*jj). Inline per-head
// Sinkhorn (R8-verified exp2/log2 form). j-loop = R5-verified barrier-free
// direct-L2 body with register prefetch. LDS only 35840B -> 2 blocks/CU.
__global__ __launch_bounds__(512) void attn_kernel(
    const u16* __restrict__ qb, const u16* __restrict__ kb,
    const u16* __restrict__ vtb, const float* __restrict__ qsum,
    const float* __restrict__ ksum, const float* __restrict__ gu,
    float* __restrict__ out)
{
  __shared__ __align__(16) unsigned char smem[35840];
  // reduction aliases (used after sinkhorn region is dead)
  float (*redh)[2][32][68] = (float (*)[2][32][68])smem;       // 34816 B
  float (*cbuf)[32] = (float (*)[32])(smem + 34816);           // 1024 B
  // sinkhorn scratch (bytes 0..21119; overlaps redh only, not cbuf)
  float* qs    = (float*)smem;                 // [32][65]
  float* ks    = qs + 32 * 65;                 // [32][65]
  float* rbufS = ks + 32 * 65;                 // [32][33]
  float* colb  = rbufS + 32 * 33;              // [32]
  float* RmRow = colb + 32;                    // [32]

  const int bh  = blockIdx.x & 7;
  const int i   = blockIdx.x >> 3;
  const int t   = threadIdx.x;
  const int w   = t >> 6;
  const int n   = w & 1;
  const int g   = w >> 1;
  const int lane = t & 63;
  const int l31 = lane & 31;
  const int hi  = lane >> 5;

  const u16* qtile = qb + ((size_t)(bh * NB + i)) * 4096;
  const u16* kbh   = kb + (size_t)bh * NB * 4096;
  const u16* vbh   = vtb + (size_t)bh * NB * 4096;

  // fragment-major direct global load: 1KB contiguous per instruction
#define LOADG(dst, base)                                                      \
  {                                                                           \
    _Pragma("unroll") for (int m = 0; m < 2; ++m)                             \
    _Pragma("unroll") for (int s = 0; s < 4; ++s)                             \
      dst[m][s] = *(const bf16x8*)((base) + ((size_t)((m * 4 + s) * 64 + lane)) * 8); \
  }

  // persistent Q B-fragments
  bf16x8 qB[4];
#pragma unroll
  for (int s = 0; s < 4; ++s)
    qB[s] = *(const bf16x8*)(qtile + ((size_t)((n * 4 + s) * 64 + lane)) * 8);

  // ---- inline per-head Sinkhorn (R8-verified exp2/log2 form) ----
  float rij8[8];
  {
    const float L2E = 1.4426950408889634f;
    const float LN2 = 0.6931471805599453f;

    {
      int idx = t * 4;  // 0..2047
      float4 qv = *(const float4*)(qsum + bh * 2048 + idx);
      float4 kv = *(const float4*)(ksum + bh * 2048 + idx);
      int b = idx >> 6, e = idx & 63;
      float* qd = qs + b * 65 + e;
      qd[0] = qv.x; qd[1] = qv.y; qd[2] = qv.z; qd[3] = qv.w;
      float* kd = ks + b * 65 + e;
      kd[0] = kv.x; kd[1] = kv.y; kd[2] = kv.z; kd[3] = kv.w;
    }
    __syncthreads();

    const int G = t >> 5;   // 0..15
    const int j = t & 31;
    float rr2[2];
#pragma unroll
    for (int x = 0; x < 2; ++x) {
      int ii = G + 16 * x;
      float acc = 0.f;
      for (int e = 0; e < 64; ++e) acc += qs[ii * 65 + e] * ks[j * 65 + e];
      acc *= 0.125f;
      float u = gu[bh * 1024 + ii * 32 + j];
      float gg = -logf(-logf(u + 1e-6f) + 1e-6f);
      rr2[x] = (logf(fmaxf(acc, 0.f) + 1e-6f) + gg) * (1.0f / 0.75f);
    }

    for (int it = 0; it < 7; ++it) {
#pragma unroll
      for (int x = 0; x < 2; ++x) {
        float s = exp2x(rr2[x] * L2E);
        s += __shfl_xor(s, 16, 32);
        s += __shfl_xor(s, 8, 32);
        s += __shfl_xor(s, 4, 32);
        s += __shfl_xor(s, 2, 32);
        s += __shfl_xor(s, 1, 32);
        rr2[x] -= log2x(fmaxf(s, 1e-30f)) * LN2;
      }
#pragma unroll
      for (int x = 0; x < 2; ++x) rbufS[(G + 16 * x) * 33 + j] = rr2[x];
      __syncthreads();
#pragma unroll
      for (int x = 0; x < 2; ++x) {
        int col = G + 16 * x;
        float s2 = exp2x(rbufS[j * 33 + col] * L2E);
        s2 += __shfl_xor(s2, 16, 32);
        s2 += __shfl_xor(s2, 8, 32);
        s2 += __shfl_xor(s2, 4, 32);
        s2 += __shfl_xor(s2, 2, 32);
        s2 += __shfl_xor(s2, 1, 32);
        if (j == 0) colb[col] = log2x(fmaxf(s2, 1e-30f)) * LN2;
      }
      __syncthreads();
#pragma unroll
      for (int x = 0; x < 2; ++x) rr2[x] -= colb[j];
    }

#pragma unroll
    for (int x = 0; x < 2; ++x) {
      if (G + 16 * x == i) {
        float R = exp2x(rr2[x] * L2E);
        RmRow[j] = (R > 1e-3f) ? R : 0.f;
      }
    }
    __syncthreads();
#pragma unroll
    for (int jj = 0; jj < 8; ++jj) rij8[jj] = RmRow[g + 4 * jj];
  }

  // first j tile (j = g), latency covered by the self phase
  bf16x8 kA[2][4], vB[2][4];
  LOADG(kA, kbh + (size_t)g * 4096);
  LOADG(vB, vbh + (size_t)g * 4096);

  // ---- self phase: S_self^T, m0, S0, psA (R4/R5-verified) ----
  float m0, S0;
  bf16x8 psA[4];
  {
    const u16* kib = kbh + (size_t)i * 4096;
    bf16x8 kAi[2][4];
    LOADG(kAi, kib);
    f32x16 aS0, aS1;
#pragma unroll
    for (int r = 0; r < 16; ++r) { aS0[r] = 0.f; aS1[r] = 0.f; }
#pragma unroll
    for (int s = 0; s < 4; ++s) {
      aS0 = __builtin_amdgcn_mfma_f32_32x32x16_bf16(kAi[0][s], qB[s], aS0, 0, 0, 0);
      aS1 = __builtin_amdgcn_mfma_f32_32x32x16_bf16(kAi[1][s], qB[s], aS1, 0, 0, 0);
    }
    float mx[16];
#pragma unroll
    for (int r = 0; r < 16; ++r) mx[r] = fmaxf(aS0[r], aS1[r]);
#pragma unroll
    for (int off = 8; off > 0; off >>= 1)
#pragma unroll
      for (int r = 0; r < off; ++r) mx[r] = fmaxf(mx[r], mx[r + off]);
    float mm = fmaxf(mx[0], __shfl_xor(mx[0], 32, 64));
#pragma unroll
    for (int r = 0; r < 16; ++r) { aS0[r] = exp2x(aS0[r] - mm); aS1[r] = exp2x(aS1[r] - mm); }
    float sm[16];
#pragma unroll
    for (int r = 0; r < 16; ++r) sm[r] = aS0[r] + aS1[r];
#pragma unroll
    for (int off = 8; off > 0; off >>= 1)
#pragma unroll
      for (int r = 0; r < off; ++r) sm[r] += sm[r + off];
    S0 = sm[0] + __shfl_xor(sm[0], 32, 64);
    m0 = mm;
    psA[0] = pack8v(aS0, 0);
    psA[1] = pack8v(aS0, 8);
    psA[2] = pack8v(aS1, 0);
    psA[3] = pack8v(aS1, 8);
  }

  f32x16 outAcc[2];
#pragma unroll
  for (int nv = 0; nv < 2; ++nv)
#pragma unroll
    for (int e = 0; e < 16; ++e) outAcc[nv][e] = 0.f;
  float cacc = 0.f;

  // ---- j loop: 8 barrier-free iterations, direct L2, reg prefetch ----
#pragma unroll
  for (int jj = 0; jj < 8; ++jj) {
    const int j = g + 4 * jj;
    const float rij = rij8[jj];

    f32x16 a0, a1;
#pragma unroll
    for (int r = 0; r < 16; ++r) { a0[r] = 0.f; a1[r] = 0.f; }
    __builtin_amdgcn_s_setprio(1);
#pragma unroll
    for (int s = 0; s < 4; ++s) {
      a0 = __builtin_amdgcn_mfma_f32_32x32x16_bf16(kA[0][s], qB[s], a0, 0, 0, 0);
      a1 = __builtin_amdgcn_mfma_f32_32x32x16_bf16(kA[1][s], qB[s], a1, 0, 0, 0);
    }
    __builtin_amdgcn_s_setprio(0);

    if (jj < 7) LOADG(kA, kbh + (size_t)(j + 4) * 4096);  // kA dead: prefetch

    float mx[16];
#pragma unroll
    for (int r = 0; r < 16; ++r) mx[r] = fmaxf(a0[r], a1[r]);
#pragma unroll
    for (int off = 8; off > 0; off >>= 1)
#pragma unroll
      for (int r = 0; r < off; ++r) mx[r] = fmaxf(mx[r], mx[r + off]);
    float mc = fmaxf(mx[0], __shfl_xor(mx[0], 32, 64));
    float mj = fmaxf(m0, mc);
#pragma unroll
    for (int r = 0; r < 16; ++r) { a0[r] = exp2x(a0[r] - mj); a1[r] = exp2x(a1[r] - mj); }
    float sm[16];
#pragma unroll
    for (int r = 0; r < 16; ++r) sm[r] = a0[r] + a1[r];
#pragma unroll
    for (int off = 8; off > 0; off >>= 1)
#pragma unroll
      for (int r = 0; r < off; ++r) sm[r] += sm[r + off];
    float ssum = sm[0] + __shfl_xor(sm[0], 32, 64);
    float e0 = exp2x(m0 - mj);
    float den = S0 * e0 + ssum;
    float inv = rij / den;
    cacc += e0 * inv;
#pragma unroll
    for (int r = 0; r < 16; ++r) { a0[r] *= inv; a1[r] *= inv; }

    __builtin_amdgcn_s_setprio(1);
#pragma unroll
    for (int s = 0; s < 4; ++s) {
      bf16x8 wf = (s < 2) ? pack8v(a0, 8 * (s & 1)) : pack8v(a1, 8 * (s & 1));
      outAcc[0] = __builtin_amdgcn_mfma_f32_32x32x16_bf16(wf, vB[0][s], outAcc[0], 0, 0, 0);
      outAcc[1] = __builtin_amdgcn_mfma_f32_32x32x16_bf16(wf, vB[1][s], outAcc[1], 0, 0, 0);
    }
    __builtin_amdgcn_s_setprio(0);

    if (jj < 7) LOADG(vB, vbh + (size_t)(j + 4) * 4096);  // vB dead: prefetch
  }

  // ---- per-wave self term: out += cacc(row) * psA @ V_i ----
  {
    const u16* vib = vbh + (size_t)i * 4096;
    bf16x8 vBi[2][4];
    LOADG(vBi, vib);
    f32x16 U[2];
#pragma unroll
    for (int nv = 0; nv < 2; ++nv)
#pragma unroll
      for (int e = 0; e < 16; ++e) U[nv][e] = 0.f;
#pragma unroll
    for (int s = 0; s < 4; ++s) {
      U[0] = __builtin_amdgcn_mfma_f32_32x32x16_bf16(psA[s], vBi[0][s], U[0], 0, 0, 0);
      U[1] = __builtin_amdgcn_mfma_f32_32x32x16_bf16(psA[s], vBi[1][s], U[1], 0, 0, 0);
    }
    if (hi == 0) cbuf[w][l31] = cacc;
    __syncthreads();
#pragma unroll
    for (int r = 0; r < 16; ++r) {
      int row = (r & 3) + 8 * (r >> 2) + 4 * hi;
      float cr = cbuf[w][row];
      outAcc[0][r] += U[0][r] * cr;
      outAcc[1][r] += U[1][r] * cr;
    }
  }

  // ---- per-n 4-wave reduction tree ----
#define RED_W(buf)                                                         \
  {                                                                        \
    _Pragma("unroll") for (int ne = 0; ne < 2; ++ne)                       \
    _Pragma("unroll") for (int r = 0; r < 16; ++r) {                       \
      int row = (r & 3) + 8 * (r >> 2) + 4 * hi;                           \
      (buf)[row][l31 + 32 * ne] = outAcc[ne][r];                           \
    }                                                                      \
  }
#define RED_A(buf)                                                         \
  {                                                                        \
    _Pragma("unroll") for (int ne = 0; ne < 2; ++ne)                       \
    _Pragma("unroll") for (int r = 0; r < 16; ++r) {                       \
      int row = (r & 3) + 8 * (r >> 2) + 4 * hi;                           \
      outAcc[ne][r] += (buf)[row][l31 + 32 * ne];                          \
    }                                                                      \
  }

  if (g >= 2) RED_W(redh[n][g - 2]);
  __syncthreads();
  if (g < 2) RED_A(redh[n][g]);
  __syncthreads();
  if (g == 1) RED_W(redh[n][0]);
  __syncthreads();
  if (g == 0) {
    RED_A(redh[n][0]);
    RED_W(redh[n][0]);
  }
  __syncthreads();

  // coalesced store
  {
    int row = t >> 3;
    int nr = row >> 5, lrow = row & 31;
    int col0 = (t & 7) * 8;
    float4 a = *(const float4*)&redh[nr][0][lrow][col0];
    float4 b = *(const float4*)&redh[nr][0][lrow][col0 + 4];
    float* ob = out + ((size_t)bh * TT + i * SS + row) * DD + col0;
    *(float4*)ob = a;
    *(float4*)(ob + 4) = b;
  }
#undef LOADG
#undef RED_W
#undef RED_A
}

extern "C" void kernel_launch(void* const* d_in, const int* in_sizes, int n_in,
                              void* d_out, int out_size, void* d_ws, size_t ws_size,
                              hipStream_t stream) {
  (void)in_sizes; (void)n_in; (void)out_size; (void)ws_size;
  const float* q  = (const float*)d_in[0];
  const float* k  = (const float*)d_in[1];
  const float* v  = (const float*)d_in[2];
  const float* gu = (const float*)d_in[3];
  float* out = (float*)d_out;

  char* wsb = (char*)d_ws;
  u16* qb   = (u16*)(wsb);
  u16* kb   = (u16*)(wsb + (1 << 21));
  u16* vtb  = (u16*)(wsb + (2 << 21));
  float* qsum = (float*)(wsb + (3 << 21));
  float* ksum = (float*)(wsb + (3 << 21) + (1 << 16));

  prep_kernel<<<256, 256, 0, stream>>>(q, k, v, qb, kb, vtb, qsum, ksum);
  attn_kernel<<<BH * NB, 512, 0, stream>>>(qb, kb, vtb, qsum, ksum, gu, out);
}